// Round 6
// baseline (202.380 us; speedup 1.0000x reference)
//
#include <hip/hip_runtime.h>
#include <hip/hip_bf16.h>

#define TILE 256   // nodes per block in phase 1

typedef float f32x4 __attribute__((ext_vector_type(4)));
typedef int   i32x4 __attribute__((ext_vector_type(4)));

__device__ __forceinline__ float fast_tanh(float x) {
    float ax = fabsf(x);
    float t = __expf(-2.f * ax);                       // in (0,1], no overflow
    float r = (1.f - t) * __builtin_amdgcn_rcpf(1.f + t);
    return copysignf(r, x);
}

__device__ __forceinline__ float fast_sigmoid(float s) {
    return __builtin_amdgcn_rcpf(1.f + __expf(-s));
}

// Phase 1: P[n][0:8] = X[n]·W1[0:64,:] + b1 ; P[n][8:16] = X[n]·W1[64:128,:]
// Decomposition matches phase2: blockIdx&7 = batch -> batch b's node tiles run
// on XCD b, so P[b] (3.2MB) is written into (and stays resident in) XCD b's
// 4MiB L2, which phase2 (same pinning) then gathers from as local L2 hits.
// 32KB LDS (2 chunks of 128B per node row) -> 5 blocks/CU (20 waves/CU).
// XOR-swizzled [node][8] f32x4 layout: conflict-free on write & read sides.
__global__ __launch_bounds__(256, 5) void phase1_kernel(
    const float* __restrict__ X, const float* __restrict__ W1,
    const float* __restrict__ b1, float* __restrict__ P, int N, int tiles_pb) {
    __shared__ f32x4 lds[TILE * 8];   // 32 KB
    int t = threadIdx.x;
    int b = blockIdx.x & 7;
    int tile = blockIdx.x >> 3;
    int base = tile * TILE;           // node offset within batch

    float acc[16];
#pragma unroll
    for (int j = 0; j < 8; ++j) acc[j] = b1[j];      // uniform -> s_load
#pragma unroll
    for (int j = 8; j < 16; ++j) acc[j] = 0.f;

    const f32x4* Xv = (const f32x4*)X + ((size_t)b * N << 4);
    int sw = t & 7;

#pragma unroll
    for (int c = 0; c < 2; ++c) {
        // Stage chunk c: 2048 f32x4, 8 per thread; each node contributes one
        // contiguous 128B half-row -> full-line global reads.
#pragma unroll
        for (int k = 0; k < 8; ++k) {
            int s = t + (k << 8);
            int node = s >> 3, f4l = s & 7;
            int ln = base + node;
            ln = (ln < N) ? ln : (N - 1);            // clamp: in-bounds
            f32x4 v = __builtin_nontemporal_load(
                Xv + ((size_t)ln << 4) + (c << 3) + f4l);
            lds[(node << 3) | (f4l ^ (node & 7))] = v;
        }
        __syncthreads();

        // Compute: thread t owns node (base + t); 32 dims this chunk.
        const f32x4* row = lds + (t << 3);
#pragma unroll
        for (int j8 = 0; j8 < 8; ++j8) {
            f32x4 xv = row[j8 ^ sw];                 // de-swizzle read
#pragma unroll
            for (int dd = 0; dd < 4; ++dd) {
                int d = (c << 5) + (j8 << 2) + dd;
                float xs = xv[dd];
                const float* wo = W1 + d * 8;        // uniform -> s_load
                const float* wi = W1 + (64 + d) * 8;
#pragma unroll
                for (int j = 0; j < 8; ++j) {
                    acc[j]     += xs * wo[j];
                    acc[8 + j] += xs * wi[j];
                }
            }
        }
        if (c == 0) __syncthreads();                 // before re-staging
    }

    int ln = base + t;
    if (ln < N) {
        f32x4* dst = (f32x4*)(P + (((size_t)b * N + ln) << 4));
        dst[0] = f32x4{acc[0],  acc[1],  acc[2],  acc[3]};
        dst[1] = f32x4{acc[4],  acc[5],  acc[6],  acc[7]};
        dst[2] = f32x4{acc[8],  acc[9],  acc[10], acc[11]};
        dst[3] = f32x4{acc[12], acc[13], acc[14], acc[15]};
    }
}

// Phase 2: per edge: h = tanh(P_o[ro] + P_i[ri]); out = sigmoid(h·W2 + b2)
// blockIdx.x & 7 == batch -> same XCD as the phase1 writer of this P slice.
// 4 edges/thread: int4 nt index loads, 16 gathers issued before any math,
// f32x4 nt output store (E % 4 == 0 -> no tail).
__global__ __launch_bounds__(256) void phase2_kernel(
    const int* __restrict__ Ri, const int* __restrict__ Ro,
    const float* __restrict__ P, const float* __restrict__ W2,
    const float* __restrict__ b2, float* __restrict__ out,
    int E, int N) {
    int b = blockIdx.x & 7;
    int e0 = (((blockIdx.x >> 3) << 8) + threadIdx.x) << 2;
    if (e0 >= E) return;
    size_t idx0 = (size_t)b * E + e0;
    i32x4 ro4 = __builtin_nontemporal_load((const i32x4*)(Ro + idx0));
    i32x4 ri4 = __builtin_nontemporal_load((const i32x4*)(Ri + idx0));

    const f32x4* Pv = (const f32x4*)P;
    int nb = b * N;
    f32x4 a0[4], a1[4], c0[4], c1[4];
#pragma unroll
    for (int k = 0; k < 4; ++k) {                    // all 16 gathers in flight
        int rb = (nb + ro4[k]) << 2;                 // f32x4 units; row = 4
        int ib = (nb + ri4[k]) << 2;
        a0[k] = Pv[rb];     a1[k] = Pv[rb + 1];      // P_o(ro) (b1 folded in)
        c0[k] = Pv[ib + 2]; c1[k] = Pv[ib + 3];      // P_i(ri)
    }

    f32x4 w2a = *(const f32x4*)W2;                   // uniform -> s_load
    f32x4 w2b = *(const f32x4*)(W2 + 4);
    float bias2 = b2[0];
    f32x4 res;
#pragma unroll
    for (int k = 0; k < 4; ++k) {
        float s = bias2;
#pragma unroll
        for (int j = 0; j < 4; ++j) {
            s += fast_tanh(a0[k][j] + c0[k][j]) * w2a[j];
            s += fast_tanh(a1[k][j] + c1[k][j]) * w2b[j];
        }
        res[k] = fast_sigmoid(s);
    }
    __builtin_nontemporal_store(res, (f32x4*)(out + idx0));
}

// Fallback if workspace is too small: one-pass per-edge evaluation.
__global__ __launch_bounds__(256) void direct_kernel(
    const float* __restrict__ X, const int* __restrict__ Ri, const int* __restrict__ Ro,
    const float* __restrict__ W1, const float* __restrict__ b1,
    const float* __restrict__ W2, const float* __restrict__ b2,
    float* __restrict__ out, int E, int N) {
    int b = blockIdx.x & 7;
    int e = ((blockIdx.x >> 3) << 8) + threadIdx.x;
    if (e >= E) return;
    size_t idx = (size_t)b * E + e;
    int ro = Ro[idx], ri = Ri[idx];
    const float* xo = X + (size_t)(b * N + ro) * 64;
    const float* xi = X + (size_t)(b * N + ri) * 64;
    float acc[8];
#pragma unroll
    for (int j = 0; j < 8; ++j) acc[j] = b1[j];
#pragma unroll
    for (int dc = 0; dc < 64; dc += 4) {
        float4 ov = *(const float4*)(xo + dc);
        float4 iv = *(const float4*)(xi + dc);
#pragma unroll
        for (int dd = 0; dd < 4; ++dd) {
            float os = (dd == 0) ? ov.x : (dd == 1) ? ov.y : (dd == 2) ? ov.z : ov.w;
            float is = (dd == 0) ? iv.x : (dd == 1) ? iv.y : (dd == 2) ? iv.z : iv.w;
            const float* wo = W1 + (dc + dd) * 8;
            const float* wi = W1 + (64 + dc + dd) * 8;
#pragma unroll
            for (int j = 0; j < 8; ++j)
                acc[j] += os * wo[j] + is * wi[j];
        }
    }
    float4 w2a = *(const float4*)W2;
    float4 w2b = *(const float4*)(W2 + 4);
    float w2v[8] = {w2a.x, w2a.y, w2a.z, w2a.w, w2b.x, w2b.y, w2b.z, w2b.w};
    float s = b2[0];
#pragma unroll
    for (int j = 0; j < 8; ++j) s += fast_tanh(acc[j]) * w2v[j];
    out[idx] = fast_sigmoid(s);
}

extern "C" void kernel_launch(void* const* d_in, const int* in_sizes, int n_in,
                              void* d_out, int out_size, void* d_ws, size_t ws_size,
                              hipStream_t stream) {
    const float* X  = (const float*)d_in[0];
    const int*   Ri = (const int*)d_in[1];
    const int*   Ro = (const int*)d_in[2];
    const float* W1 = (const float*)d_in[3];
    const float* b1 = (const float*)d_in[4];
    const float* W2 = (const float*)d_in[5];
    const float* b2 = (const float*)d_in[6];
    float* out = (float*)d_out;

    const int B = 8;
    const int N = in_sizes[0] / (B * 64);   // 50000
    const int E = in_sizes[1] / B;          // 200000
    const int BN = B * N;

    size_t needP = (size_t)BN * 16 * sizeof(float);

    if (ws_size >= needP) {
        float* P = (float*)d_ws;
        int tiles_pb = (N + TILE - 1) / TILE;          // 196
        phase1_kernel<<<8 * tiles_pb, 256, 0, stream>>>(X, W1, b1, P, N, tiles_pb);
        int bpb2 = (E + 1023) / 1024;                  // 4 edges/thread
        phase2_kernel<<<8 * bpb2, 256, 0, stream>>>(Ri, Ro, P, W2, b2, out, E, N);
    } else {
        int bpb = (E + 255) / 256;
        direct_kernel<<<8 * bpb, 256, 0, stream>>>(X, Ri, Ro, W1, b1, W2, b2, out, E, N);
    }
}